// Round 2
// baseline (656.209 us; speedup 1.0000x reference)
//
#include <hip/hip_runtime.h>

// Problem constants
#define BB 64
#define SS 2048
#define DD 512

typedef __attribute__((ext_vector_type(8))) short bf16x8;
typedef __attribute__((ext_vector_type(4))) float f32x4;

// fp32 -> bf16 bits, round-to-nearest-even
__device__ __forceinline__ unsigned f2bf(float f) {
    unsigned u = __float_as_uint(f);
    u += 0x7FFFu + ((u >> 16) & 1u);
    return u >> 16;
}

__device__ __forceinline__ float fast_tanh(float x) {
    float ax = fabsf(x);
    float e = __expf(-2.0f * ax);                       // (0,1], never overflows
    float t = (1.0f - e) * __builtin_amdgcn_rcpf(1.0f + e);
    return x < 0.0f ? -t : t;
}

// ---------------------------------------------------------------------------
// Prep 1: Bt[n][k] = bf16(W_t[512+k][n]).  64x64 LDS tile transpose.
__global__ void prep_w(const float* __restrict__ W, short* __restrict__ Bt) {
    __shared__ float tile[64][65];
    int kt = blockIdx.x >> 3;      // 8 x 8 tiles
    int nt = blockIdx.x & 7;
    int t = threadIdx.x;
    int c = t & 63;
    int rbase = (t >> 6) * 16;
    #pragma unroll
    for (int i = 0; i < 16; ++i) {
        int r = rbase + i;
        tile[r][c] = W[(size_t)(512 + kt * 64 + r) * DD + nt * 64 + c];
    }
    __syncthreads();
    #pragma unroll
    for (int i = 0; i < 16; ++i) {
        int r = rbase + i;
        Bt[(size_t)(nt * 64 + r) * DD + kt * 64 + c] = (short)f2bf(tile[c][r]);
    }
}

// Prep 2: p[b][d] = sum_e dec[b][e] * W_t[e][d] + b_t[d]   (fp32, exact)
__global__ void prep_p(const float* __restrict__ dec, const float* __restrict__ W,
                       const float* __restrict__ bt, float* __restrict__ p) {
    int b = blockIdx.x;
    int d = blockIdx.y * 256 + threadIdx.x;
    float acc = bt[d];
    const float* dv = dec + (size_t)b * DD;
    #pragma unroll 8
    for (int e = 0; e < DD; ++e)
        acc += dv[e] * W[(size_t)e * DD + d];
    p[(size_t)b * DD + d] = acc;
}

// ---------------------------------------------------------------------------
// Fused v2: 64-row chunk, 1024 threads (16 waves = 2 m-groups x 8 n-slices).
// enc tile staged ONCE: fp32 kept in registers (stg[8], exact ctx epilogue),
// bf16-hi written to a single 64 KB LDS tile for MFMA. 8 k-slabs of 64 cols,
// distance-4 register prefetch, one barrier per slab. B-frags straight from
// L2 (Bt = 512 KB resident). LDS 68 KB (ctx-reduce buffer aliases dead Ahi)
// -> 16 waves/CU with __launch_bounds__(1024,4) capping VGPR at 128.
// Round-1 lesson: 138 KB LDS -> 1 block/CU, 23% occ, latency-bound at 257 us.
__global__ __launch_bounds__(1024, 4)
void fused_k(const float* __restrict__ enc, const short* __restrict__ Bt,
             const float* __restrict__ p, const float* __restrict__ va,
             float* __restrict__ score, float* __restrict__ ml,
             float* __restrict__ pctx) {
    // [0, 65536)      : Ahi bf16 tile [64][512], row stride 1024 B, XOR-swizzled
    // [0, 32768)      : (alias, after GEMM) red fp32 [16][512] ctx reduce
    // [65536, +2048)  : sp fp32 [16][32] cross-wave score reduce
    // [67584, +256)   : elds fp32 [64]
    __shared__ char smem[65536 + 2048 + 256];
    char* AhiB = smem;
    float (*red)[512] = (float (*)[512])smem;
    float (*sp)[32]   = (float (*)[32])(smem + 65536);
    float* elds       = (float*)(smem + 67584);

    const int tid  = threadIdx.x;
    const int wave = tid >> 6;
    const int lane = tid & 63;
    const int lm   = lane & 15;
    const int lq   = lane >> 4;
    const int wm   = wave >> 3;            // m-group: rows [wm*32, wm*32+32)
    const int wn   = wave & 7;             // n-slice: cols [wn*64, wn*64+64)
    const int blk  = blockIdx.x;
    const int b    = blk >> 5;             // 32 chunks per batch
    const size_t m0 = (size_t)blk * 64;

    // ---- staging geometry: thread t -> row t>>4, 4 floats at col (t&15)*4 + slab*64
    const int srow = tid >> 4;
    const int sc   = tid & 15;
    const unsigned srowB = (unsigned)srow * 1024u;
    const unsigned swsr  = (unsigned)(srow & 7) << 4;
    const float* aptr = enc + (m0 + (size_t)srow) * DD + sc * 4;

    // ---- compute geometry
    const unsigned swlm = (unsigned)(lm & 7) << 4;
    const unsigned arow0 = (unsigned)(wm * 32 + lm) * 1024u;
    const unsigned arow1 = arow0 + 16u * 1024u;
    const short* Bw = Bt + (size_t)(wn * 64 + lm) * DD + lq * 8;

    f32x4 acc[2][4];
    #pragma unroll
    for (int i = 0; i < 2; ++i)
        #pragma unroll
        for (int j = 0; j < 4; ++j)
            acc[i][j] = (f32x4){0.f, 0.f, 0.f, 0.f};

    // ---- prologue: issue slabs 0..3; write slab 0 (hi only)
    f32x4 stg[8];
    #pragma unroll
    for (int s = 0; s < 4; ++s)
        stg[s] = *(const f32x4*)(aptr + s * 64);
    {
        uint2 hv;
        hv.x = f2bf(stg[0].x) | (f2bf(stg[0].y) << 16);
        hv.y = f2bf(stg[0].z) | (f2bf(stg[0].w) << 16);
        *(uint2*)(AhiB + (srowB + ((sc * 8u) ^ swsr))) = hv;
    }
    __syncthreads();

    #pragma unroll
    for (int kt = 0; kt < 8; ++kt) {
        // distance-4 prefetch: slab kt+4 (consumed as LDS write at iter kt+3)
        if (kt < 4)
            stg[kt + 4] = *(const f32x4*)(aptr + (kt + 4) * 64);

        // A frags from swizzled LDS (slab kt = byte cols [kt*128, kt*128+128))
        const unsigned kb = (unsigned)kt * 128u;
        bf16x8 af[2][2];
        af[0][0] = *(const bf16x8*)(AhiB + arow0 + ((kb + 0u  + lq * 16u) ^ swlm));
        af[0][1] = *(const bf16x8*)(AhiB + arow0 + ((kb + 64u + lq * 16u) ^ swlm));
        af[1][0] = *(const bf16x8*)(AhiB + arow1 + ((kb + 0u  + lq * 16u) ^ swlm));
        af[1][1] = *(const bf16x8*)(AhiB + arow1 + ((kb + 64u + lq * 16u) ^ swlm));

        // B frags from L2, 16 MFMA (k-step 64 = 2 halves)
        #pragma unroll
        for (int nf = 0; nf < 4; ++nf) {
            const short* bp = Bw + nf * 16 * DD + kt * 64;
            bf16x8 b0 = *(const bf16x8*)(bp);
            bf16x8 b1 = *(const bf16x8*)(bp + 32);
            acc[0][nf] = __builtin_amdgcn_mfma_f32_16x16x32_bf16(af[0][0], b0, acc[0][nf], 0, 0, 0);
            acc[1][nf] = __builtin_amdgcn_mfma_f32_16x16x32_bf16(af[1][0], b0, acc[1][nf], 0, 0, 0);
            acc[0][nf] = __builtin_amdgcn_mfma_f32_16x16x32_bf16(af[0][1], b1, acc[0][nf], 0, 0, 0);
            acc[1][nf] = __builtin_amdgcn_mfma_f32_16x16x32_bf16(af[1][1], b1, acc[1][nf], 0, 0, 0);
        }

        // write slab kt+1 (distinct LDS region -> no WAR with slab kt reads)
        if (kt < 7) {
            f32x4 x = stg[kt + 1];
            uint2 hv;
            hv.x = f2bf(x.x) | (f2bf(x.y) << 16);
            hv.y = f2bf(x.z) | (f2bf(x.w) << 16);
            *(uint2*)(AhiB + (srowB + (((unsigned)((kt + 1) * 128) + sc * 8u) ^ swsr))) = hv;
        }
        __syncthreads();
    }

    // ---- epilogue 1: tanh + dot v over this wave's n-slice
    const float* pb = p + (size_t)b * DD;
    float rowsum[2][4];
    #pragma unroll
    for (int mf = 0; mf < 2; ++mf)
        #pragma unroll
        for (int r = 0; r < 4; ++r) rowsum[mf][r] = 0.f;

    #pragma unroll
    for (int nf = 0; nf < 4; ++nf) {
        int n = wn * 64 + nf * 16 + lm;
        float pv = pb[n];
        float vv = va[n];
        #pragma unroll
        for (int mf = 0; mf < 2; ++mf)
            #pragma unroll
            for (int r = 0; r < 4; ++r)
                rowsum[mf][r] += fast_tanh(pv + acc[mf][nf][r]) * vv;
    }
    #pragma unroll
    for (int mf = 0; mf < 2; ++mf)
        #pragma unroll
        for (int r = 0; r < 4; ++r) {
            float s = rowsum[mf][r];
            s += __shfl_xor(s, 1);
            s += __shfl_xor(s, 2);
            s += __shfl_xor(s, 4);
            s += __shfl_xor(s, 8);
            rowsum[mf][r] = s;
        }
    if (lm == 0) {
        #pragma unroll
        for (int mf = 0; mf < 2; ++mf)
            #pragma unroll
            for (int r = 0; r < 4; ++r)
                sp[wave][mf * 16 + lq * 4 + r] = rowsum[mf][r];
    }
    __syncthreads();

    // ---- epilogue 2: full scores for 64 rows, chunk-local softmax partials
    if (tid < 64) {
        const int base = (tid >> 5) * 8;     // wm of this row
        const int rl = tid & 31;
        float s = 0.f;
        #pragma unroll
        for (int w = 0; w < 8; ++w) s += sp[base + w][rl];
        score[m0 + tid] = s;
        float mx = s;
        #pragma unroll
        for (int off = 32; off > 0; off >>= 1) mx = fmaxf(mx, __shfl_xor(mx, off));
        float e = __expf(s - mx);
        float l = e;
        #pragma unroll
        for (int off = 32; off > 0; off >>= 1) l += __shfl_xor(l, off);
        elds[tid] = e;
        if (tid == 0) {
            ml[(size_t)blk * 2]     = mx;
            ml[(size_t)blk * 2 + 1] = l;
        }
    }
    __syncthreads();

    // ---- epilogue 3: ctx partial from EXACT fp32 registers.
    // Wave covers rows [wave*4, wave*4+4); shfl-reduce over the 4 rows,
    // lanes 0..15 write the per-wave partial into red (aliases dead Ahi).
    {
        float ev = elds[srow];
        #pragma unroll
        for (int s = 0; s < 8; ++s) {
            float v0 = ev * stg[s].x;
            float v1 = ev * stg[s].y;
            float v2 = ev * stg[s].z;
            float v3 = ev * stg[s].w;
            v0 += __shfl_xor(v0, 16); v0 += __shfl_xor(v0, 32);
            v1 += __shfl_xor(v1, 16); v1 += __shfl_xor(v1, 32);
            v2 += __shfl_xor(v2, 16); v2 += __shfl_xor(v2, 32);
            v3 += __shfl_xor(v3, 16); v3 += __shfl_xor(v3, 32);
            if (lane < 16)
                *(f32x4*)(&red[wave][s * 64 + sc * 4]) = (f32x4){v0, v1, v2, v3};
        }
    }
    __syncthreads();
    if (tid < 512) {
        float v = 0.f;
        #pragma unroll
        for (int w = 0; w < 16; ++w) v += red[w][tid];
        pctx[(size_t)blk * 512 + tid] = v;
    }
}

// ---------------------------------------------------------------------------
// Cross-chunk softmax combine: exact global M, L; rescale pctx; write ctx
// and alignment. One block per batch.
__global__ void combine_k(const float* __restrict__ score, const float* __restrict__ ml,
                          const float* __restrict__ pctx, float* __restrict__ ctx,
                          float* __restrict__ align) {
    __shared__ float sc[32];
    __shared__ float MB, LB;
    const int b = blockIdx.x, tid = threadIdx.x;   // 256 threads
    if (tid < 32) sc[tid] = ml[(size_t)(b * 32 + tid) * 2];
    __syncthreads();
    if (tid == 0) {
        float M = sc[0];
        #pragma unroll
        for (int i = 1; i < 32; ++i) M = fmaxf(M, sc[i]);
        float L = 0.f;
        for (int i = 0; i < 32; ++i) {
            float w = __expf(sc[i] - M);
            L += w * ml[(size_t)(b * 32 + i) * 2 + 1];
            sc[i] = w;                  // only thread 0 touches sc here
        }
        MB = M;
        LB = L;
    }
    __syncthreads();
    const float M = MB, Linv = 1.0f / LB;
    float a0 = 0.f, a1 = 0.f;
    for (int i = 0; i < 32; ++i) {
        float w = sc[i];
        const float* pc = pctx + (size_t)(b * 32 + i) * 512;
        a0 += w * pc[tid];
        a1 += w * pc[tid + 256];
    }
    ctx[(size_t)b * DD + tid]       = a0 * Linv;
    ctx[(size_t)b * DD + tid + 256] = a1 * Linv;
    const float* sr = score + (size_t)b * SS;
    float* al = align + (size_t)b * SS;
    #pragma unroll
    for (int i = 0; i < 8; ++i) {
        int s = i * 256 + tid;
        al[s] = __expf(sr[s] - M) * Linv;
    }
}

// ---------------------------------------------------------------------------
extern "C" void kernel_launch(void* const* d_in, const int* in_sizes, int n_in,
                              void* d_out, int out_size, void* d_ws, size_t ws_size,
                              hipStream_t stream) {
    const float* dec = (const float*)d_in[0];  // [64,1,512]
    const float* enc = (const float*)d_in[1];  // [64,2048,512]
    const float* W   = (const float*)d_in[2];  // [1024,512]
    const float* bt  = (const float*)d_in[3];  // [512]
    const float* va  = (const float*)d_in[4];  // [512,1]

    float* out   = (float*)d_out;
    float* ctx   = out;                 // 32768 floats (output 0)
    float* align = out + BB * DD;       // 131072 floats (output 1)

    char*  ws    = (char*)d_ws;
    short* Bt    = (short*)ws;                    // 524288 B : bf16 W_enc^T [n][k]
    float* p     = (float*)(ws + 524288);         // 131072 B : dec @ W_dec + b_t
    float* score = (float*)(ws + 655360);         // 524288 B : raw scores
    float* ml    = (float*)(ws + 1179648);        //  16384 B : (max, sum) per chunk
    float* pctx  = (float*)(ws + 1196032);        // 4194304 B: partial contexts

    prep_w<<<64, 256, 0, stream>>>(W, Bt);
    prep_p<<<dim3(BB, 2), 256, 0, stream>>>(dec, W, bt, p);
    fused_k<<<BB * 32, 1024, 0, stream>>>(enc, Bt, p, va, score, ml, pctx);
    combine_k<<<BB, 256, 0, stream>>>(score, ml, pctx, ctx, align);
}

// Round 3
// 654.775 us; speedup vs baseline: 1.0022x; 1.0022x over previous
//
#include <hip/hip_runtime.h>

// Problem constants
#define BB 64
#define SS 2048
#define DD 512

typedef __attribute__((ext_vector_type(8))) short bf16x8;
typedef __attribute__((ext_vector_type(4))) float f32x4;

// fp32 -> bf16 bits, round-to-nearest-even
__device__ __forceinline__ unsigned f2bf(float f) {
    unsigned u = __float_as_uint(f);
    u += 0x7FFFu + ((u >> 16) & 1u);
    return u >> 16;
}

__device__ __forceinline__ float fast_tanh(float x) {
    float ax = fabsf(x);
    float e = __expf(-2.0f * ax);                       // (0,1], never overflows
    float t = (1.0f - e) * __builtin_amdgcn_rcpf(1.0f + e);
    return x < 0.0f ? -t : t;
}

// ---------------------------------------------------------------------------
// Prep 1: Bt[n][k] = bf16(W_t[512+k][n]).  64x64 LDS tile transpose.
__global__ void prep_w(const float* __restrict__ W, short* __restrict__ Bt) {
    __shared__ float tile[64][65];
    int kt = blockIdx.x >> 3;      // 8 x 8 tiles
    int nt = blockIdx.x & 7;
    int t = threadIdx.x;
    int c = t & 63;
    int rbase = (t >> 6) * 16;
    #pragma unroll
    for (int i = 0; i < 16; ++i) {
        int r = rbase + i;
        tile[r][c] = W[(size_t)(512 + kt * 64 + r) * DD + nt * 64 + c];
    }
    __syncthreads();
    #pragma unroll
    for (int i = 0; i < 16; ++i) {
        int r = rbase + i;
        Bt[(size_t)(nt * 64 + r) * DD + kt * 64 + c] = (short)f2bf(tile[c][r]);
    }
}

// Prep 2: p[b][d] = sum_e dec[b][e] * W_t[e][d] + b_t[d]   (fp32, exact)
__global__ void prep_p(const float* __restrict__ dec, const float* __restrict__ W,
                       const float* __restrict__ bt, float* __restrict__ p) {
    int b = blockIdx.x;
    int d = blockIdx.y * 256 + threadIdx.x;
    float acc = bt[d];
    const float* dv = dec + (size_t)b * DD;
    #pragma unroll 8
    for (int e = 0; e < DD; ++e)
        acc += dv[e] * W[(size_t)e * DD + d];
    p[(size_t)b * DD + d] = acc;
}

// ---------------------------------------------------------------------------
// Fused v3: 64-row chunk, 1024 threads (16 waves = 2 m-groups x 8 n-slices).
// Round-2 post-mortem: launch_bounds(1024,4) caps the unified file at 128;
// stg[8] fp32 retention + hi/lo conversion spilled (WRITE_SIZE 67 MB scratch).
// v3 deletes the register fat:
//  - ctx partial re-reads enc fp32 from L2/L3 after softmax (exact, no regs)
//  - BK=32 slabs, float2/thread staging, rotating stg[4] (8 VGPRs), dist-3
// Demand ~= 32 acc + ~70 arch < 128 -> no spill, 16 waves/CU.
__global__ __launch_bounds__(1024, 4)
void fused_k(const float* __restrict__ enc, const short* __restrict__ Bt,
             const float* __restrict__ p, const float* __restrict__ va,
             float* __restrict__ score, float* __restrict__ ml,
             float* __restrict__ pctx) {
    // [0, 65536)      : Ahi bf16 tile [64][512], row stride 1024 B, XOR-swizzled
    // [0, 4096)       : (alias, after GEMM) red fp32 [2][512] ctx reduce
    // [65536, +2048)  : sp fp32 [16][32] cross-wave score reduce
    // [67584, +256)   : elds fp32 [64]
    __shared__ char smem[65536 + 2048 + 256];
    char* AhiB = smem;
    float (*red)[512] = (float (*)[512])smem;
    float (*sp)[32]   = (float (*)[32])(smem + 65536);
    float* elds       = (float*)(smem + 67584);

    const int tid  = threadIdx.x;
    const int wave = tid >> 6;
    const int lane = tid & 63;
    const int lm   = lane & 15;
    const int lq   = lane >> 4;
    const int wm   = wave >> 3;            // m-group: rows [wm*32, wm*32+32)
    const int wn   = wave & 7;             // n-slice: cols [wn*64, wn*64+64)
    const int blk  = blockIdx.x;
    const int b    = blk >> 5;             // 32 chunks per batch
    const size_t m0 = (size_t)blk * 64;

    // ---- staging geometry: thread t -> row t>>4, 2 floats at col (t&15)*2
    const int srow = tid >> 4;
    const int sc   = tid & 15;
    const unsigned srowB = (unsigned)srow * 1024u;
    const unsigned swsr  = (unsigned)(srow & 7) << 4;
    const float* aptr = enc + (m0 + (size_t)srow) * DD + sc * 2;

    // ---- compute geometry
    const unsigned swlm = (unsigned)(lm & 7) << 4;
    const unsigned arow0 = (unsigned)(wm * 32 + lm) * 1024u;
    const unsigned arow1 = arow0 + 16u * 1024u;
    const short* Bw = Bt + (size_t)(wn * 64 + lm) * DD + lq * 8;

    f32x4 acc[2][4];
    #pragma unroll
    for (int i = 0; i < 2; ++i)
        #pragma unroll
        for (int j = 0; j < 4; ++j)
            acc[i][j] = (f32x4){0.f, 0.f, 0.f, 0.f};

    // ---- prologue: issue slabs 0..2 (dist-3); write slab 0
    float2 stg[4];
    stg[0] = *(const float2*)(aptr);
    stg[1] = *(const float2*)(aptr + 32);
    stg[2] = *(const float2*)(aptr + 64);
    {
        unsigned hv = f2bf(stg[0].x) | (f2bf(stg[0].y) << 16);
        *(unsigned*)(AhiB + (srowB + (((unsigned)sc * 4u) ^ swsr))) = hv;
    }
    __syncthreads();

    #pragma unroll
    for (int kt = 0; kt < 16; ++kt) {
        // distance-3 prefetch: slab kt+3 into the reg slab kt-1 vacated
        if (kt < 13)
            stg[(kt + 3) & 3] = *(const float2*)(aptr + (kt + 3) * 32);

        // A frags from swizzled LDS (slab kt = byte cols [kt*64, kt*64+64))
        const unsigned kb = (unsigned)kt * 64u;
        bf16x8 af0 = *(const bf16x8*)(AhiB + arow0 + ((kb + lq * 16u) ^ swlm));
        bf16x8 af1 = *(const bf16x8*)(AhiB + arow1 + ((kb + lq * 16u) ^ swlm));

        // B frags from L2, 8 MFMA
        #pragma unroll
        for (int nf = 0; nf < 4; ++nf) {
            bf16x8 bfr = *(const bf16x8*)(Bw + nf * 16 * DD + kt * 32);
            acc[0][nf] = __builtin_amdgcn_mfma_f32_16x16x32_bf16(af0, bfr, acc[0][nf], 0, 0, 0);
            acc[1][nf] = __builtin_amdgcn_mfma_f32_16x16x32_bf16(af1, bfr, acc[1][nf], 0, 0, 0);
        }

        // write slab kt+1 (distinct LDS region -> no WAR with slab kt reads)
        if (kt < 15) {
            float2 x = stg[(kt + 1) & 3];
            unsigned hv = f2bf(x.x) | (f2bf(x.y) << 16);
            *(unsigned*)(AhiB + (srowB + (((unsigned)((kt + 1) * 64) + sc * 4u) ^ swsr))) = hv;
        }
        __syncthreads();
    }

    // ---- epilogue 1: tanh + dot v over this wave's n-slice
    const float* pb = p + (size_t)b * DD;
    float rowsum[2][4];
    #pragma unroll
    for (int mf = 0; mf < 2; ++mf)
        #pragma unroll
        for (int r = 0; r < 4; ++r) rowsum[mf][r] = 0.f;

    #pragma unroll
    for (int nf = 0; nf < 4; ++nf) {
        int n = wn * 64 + nf * 16 + lm;
        float pv = pb[n];
        float vv = va[n];
        #pragma unroll
        for (int mf = 0; mf < 2; ++mf)
            #pragma unroll
            for (int r = 0; r < 4; ++r)
                rowsum[mf][r] += fast_tanh(pv + acc[mf][nf][r]) * vv;
    }
    #pragma unroll
    for (int mf = 0; mf < 2; ++mf)
        #pragma unroll
        for (int r = 0; r < 4; ++r) {
            float s = rowsum[mf][r];
            s += __shfl_xor(s, 1);
            s += __shfl_xor(s, 2);
            s += __shfl_xor(s, 4);
            s += __shfl_xor(s, 8);
            rowsum[mf][r] = s;
        }
    if (lm == 0) {
        #pragma unroll
        for (int mf = 0; mf < 2; ++mf)
            #pragma unroll
            for (int r = 0; r < 4; ++r)
                sp[wave][mf * 16 + lq * 4 + r] = rowsum[mf][r];
    }
    __syncthreads();

    // ---- epilogue 2: full scores for 64 rows, chunk-local softmax partials
    if (tid < 64) {
        const int base = (tid >> 5) * 8;     // wm of this row
        const int rl = tid & 31;
        float s = 0.f;
        #pragma unroll
        for (int w = 0; w < 8; ++w) s += sp[base + w][rl];
        score[m0 + tid] = s;
        float mx = s;
        #pragma unroll
        for (int off = 32; off > 0; off >>= 1) mx = fmaxf(mx, __shfl_xor(mx, off));
        float e = __expf(s - mx);
        float l = e;
        #pragma unroll
        for (int off = 32; off > 0; off >>= 1) l += __shfl_xor(l, off);
        elds[tid] = e;
        if (tid == 0) {
            ml[(size_t)blk * 2]     = mx;
            ml[(size_t)blk * 2 + 1] = l;
        }
    }
    __syncthreads();

    // ---- epilogue 3: ctx partial, exact fp32, enc re-read from L2/L3
    // (tile just streamed by this block; L3 = 256 MiB holds enc). Thread t:
    // d = t&511, s-group g = t>>9 (rows g*32 .. g*32+31).
    {
        const int d = tid & 511;
        const int g = tid >> 9;
        const float* erow = enc + (m0 + (size_t)g * 32) * DD + d;
        float v = 0.f;
        #pragma unroll
        for (int s = 0; s < 32; ++s)
            v += elds[g * 32 + s] * erow[(size_t)s * DD];
        red[g][d] = v;      // aliases dead Ahi (first 4 KB)
    }
    __syncthreads();
    if (tid < 512)
        pctx[(size_t)blk * 512 + tid] = red[0][tid] + red[1][tid];
}

// ---------------------------------------------------------------------------
// Cross-chunk softmax combine: exact global M, L; rescale pctx; write ctx
// and alignment. One block per batch.
__global__ void combine_k(const float* __restrict__ score, const float* __restrict__ ml,
                          const float* __restrict__ pctx, float* __restrict__ ctx,
                          float* __restrict__ align) {
    __shared__ float sc[32];
    __shared__ float MB, LB;
    const int b = blockIdx.x, tid = threadIdx.x;   // 256 threads
    if (tid < 32) sc[tid] = ml[(size_t)(b * 32 + tid) * 2];
    __syncthreads();
    if (tid == 0) {
        float M = sc[0];
        #pragma unroll
        for (int i = 1; i < 32; ++i) M = fmaxf(M, sc[i]);
        float L = 0.f;
        for (int i = 0; i < 32; ++i) {
            float w = __expf(sc[i] - M);
            L += w * ml[(size_t)(b * 32 + i) * 2 + 1];
            sc[i] = w;                  // only thread 0 touches sc here
        }
        MB = M;
        LB = L;
    }
    __syncthreads();
    const float M = MB, Linv = 1.0f / LB;
    float a0 = 0.f, a1 = 0.f;
    for (int i = 0; i < 32; ++i) {
        float w = sc[i];
        const float* pc = pctx + (size_t)(b * 32 + i) * 512;
        a0 += w * pc[tid];
        a1 += w * pc[tid + 256];
    }
    ctx[(size_t)b * DD + tid]       = a0 * Linv;
    ctx[(size_t)b * DD + tid + 256] = a1 * Linv;
    const float* sr = score + (size_t)b * SS;
    float* al = align + (size_t)b * SS;
    #pragma unroll
    for (int i = 0; i < 8; ++i) {
        int s = i * 256 + tid;
        al[s] = __expf(sr[s] - M) * Linv;
    }
}

// ---------------------------------------------------------------------------
extern "C" void kernel_launch(void* const* d_in, const int* in_sizes, int n_in,
                              void* d_out, int out_size, void* d_ws, size_t ws_size,
                              hipStream_t stream) {
    const float* dec = (const float*)d_in[0];  // [64,1,512]
    const float* enc = (const float*)d_in[1];  // [64,2048,512]
    const float* W   = (const float*)d_in[2];  // [1024,512]
    const float* bt  = (const float*)d_in[3];  // [512]
    const float* va  = (const float*)d_in[4];  // [512,1]

    float* out   = (float*)d_out;
    float* ctx   = out;                 // 32768 floats (output 0)
    float* align = out + BB * DD;       // 131072 floats (output 1)

    char*  ws    = (char*)d_ws;
    short* Bt    = (short*)ws;                    // 524288 B : bf16 W_enc^T [n][k]
    float* p     = (float*)(ws + 524288);         // 131072 B : dec @ W_dec + b_t
    float* score = (float*)(ws + 655360);         // 524288 B : raw scores
    float* ml    = (float*)(ws + 1179648);        //  16384 B : (max, sum) per chunk
    float* pctx  = (float*)(ws + 1196032);        // 4194304 B: partial contexts

    prep_w<<<64, 256, 0, stream>>>(W, Bt);
    prep_p<<<dim3(BB, 2), 256, 0, stream>>>(dec, W, bt, p);
    fused_k<<<BB * 32, 1024, 0, stream>>>(enc, Bt, p, va, score, ml, pctx);
    combine_k<<<BB, 256, 0, stream>>>(score, ml, pctx, ctx, align);
}

// Round 4
// 633.525 us; speedup vs baseline: 1.0358x; 1.0335x over previous
//
#include <hip/hip_runtime.h>

// Problem constants
#define BB 64
#define SS 2048
#define DD 512

typedef __attribute__((ext_vector_type(8))) short bf16x8;
typedef __attribute__((ext_vector_type(4))) float f32x4;

// fp32 -> bf16 bits, round-to-nearest-even
__device__ __forceinline__ unsigned f2bf(float f) {
    unsigned u = __float_as_uint(f);
    u += 0x7FFFu + ((u >> 16) & 1u);
    return u >> 16;
}

__device__ __forceinline__ float fast_tanh(float x) {
    float ax = fabsf(x);
    float e = __expf(-2.0f * ax);                       // (0,1], never overflows
    float t = (1.0f - e) * __builtin_amdgcn_rcpf(1.0f + e);
    return x < 0.0f ? -t : t;
}

// ---------------------------------------------------------------------------
// Prep 1: Bt[n][k] = bf16(W_t[512+k][n]).  64x64 LDS tile transpose.
__global__ void prep_w(const float* __restrict__ W, short* __restrict__ Bt) {
    __shared__ float tile[64][65];
    int kt = blockIdx.x >> 3;      // 8 x 8 tiles
    int nt = blockIdx.x & 7;
    int t = threadIdx.x;
    int c = t & 63;
    int rbase = (t >> 6) * 16;
    #pragma unroll
    for (int i = 0; i < 16; ++i) {
        int r = rbase + i;
        tile[r][c] = W[(size_t)(512 + kt * 64 + r) * DD + nt * 64 + c];
    }
    __syncthreads();
    #pragma unroll
    for (int i = 0; i < 16; ++i) {
        int r = rbase + i;
        Bt[(size_t)(nt * 64 + r) * DD + kt * 64 + c] = (short)f2bf(tile[c][r]);
    }
}

// Prep 2: p[b][d] = sum_e dec[b][e] * W_t[e][d] + b_t[d]   (fp32, exact)
__global__ void prep_p(const float* __restrict__ dec, const float* __restrict__ W,
                       const float* __restrict__ bt, float* __restrict__ p) {
    int b = blockIdx.x;
    int d = blockIdx.y * 256 + threadIdx.x;
    float acc = bt[d];
    const float* dv = dec + (size_t)b * DD;
    #pragma unroll 8
    for (int e = 0; e < DD; ++e)
        acc += dv[e] * W[(size_t)e * DD + d];
    p[(size_t)b * DD + d] = acc;
}

// ---------------------------------------------------------------------------
// Fused v4: 32-row chunk, 512 threads (8 waves, each owns a 64-col n-slice;
// all waves share the same 32 m-rows). 4096 blocks.
// Round-3 post-mortem: 1024-thread block -> 1 block/CU -> every barrier
// stalled the whole CU, and B was demand-loaded from L2 inside the consuming
// iteration (VGPR 40 = compiler did no hoisting). v4 restores overlap:
//  - 34 KB LDS + ~105 VGPR -> 2 blocks/CU (two independent barrier domains)
//  - B frags explicitly double-buffered in registers (bb[2][4]): kt+1's four
//    L2 loads issue a full iteration before use
//  - A staging: fp32->bf16, XOR-swizzled LDS [32][512], rotating stg[4], dist-3
// Epilogue: score reduce + chunk softmax partials + exact-fp32 ctx partial
// (re-reads the block's own enc tile through L2/L3).
__global__ __launch_bounds__(512, 4)
void fused_k(const float* __restrict__ enc, const short* __restrict__ Bt,
             const float* __restrict__ p, const float* __restrict__ va,
             float* __restrict__ score, float* __restrict__ ml,
             float* __restrict__ pctx) {
    // [0, 32768)      : Ahi bf16 tile [32][512], row stride 1024 B, XOR-swizzled
    // [32768, +1024)  : sp fp32 [8][32] cross-wave score reduce
    // [33792, +128)   : elds fp32 [32]
    __shared__ char smem[32768 + 1024 + 128];
    char* AhiB = smem;
    float (*sp)[32] = (float (*)[32])(smem + 32768);
    float* elds     = (float*)(smem + 33792);

    const int tid  = threadIdx.x;
    const int wave = tid >> 6;             // n-slice [wave*64, wave*64+64)
    const int lane = tid & 63;
    const int lm   = lane & 15;
    const int lq   = lane >> 4;
    const int blk  = blockIdx.x;
    const int b    = blk >> 6;             // 64 chunks per batch
    const size_t m0 = (size_t)blk * 32;    // global row base

    // ---- staging geometry: thread t -> row t>>4 (0..31), 2 floats at col (t&15)*2
    const int srow = tid >> 4;
    const int sc   = tid & 15;
    const unsigned srowB = (unsigned)srow * 1024u;
    const unsigned swsr  = (unsigned)(srow & 7) << 4;
    const float* aptr = enc + (m0 + (size_t)srow) * DD + sc * 2;

    // ---- compute geometry
    const unsigned swlm = (unsigned)(lm & 7) << 4;
    const unsigned arow0 = (unsigned)lm * 1024u;          // rows lm, lm+16
    const unsigned arow1 = arow0 + 16u * 1024u;
    const short* Bw = Bt + (size_t)(wave * 64 + lm) * DD + lq * 8;

    f32x4 acc[2][4];
    #pragma unroll
    for (int i = 0; i < 2; ++i)
        #pragma unroll
        for (int j = 0; j < 4; ++j)
            acc[i][j] = (f32x4){0.f, 0.f, 0.f, 0.f};

    // ---- prologue: B frags for kt=0; A slabs 0..2 (dist-3); write slab 0
    bf16x8 bb[2][4];
    #pragma unroll
    for (int nf = 0; nf < 4; ++nf)
        bb[0][nf] = *(const bf16x8*)(Bw + nf * 16 * DD);

    float2 stg[4];
    stg[0] = *(const float2*)(aptr);
    stg[1] = *(const float2*)(aptr + 32);
    stg[2] = *(const float2*)(aptr + 64);
    {
        unsigned hv = f2bf(stg[0].x) | (f2bf(stg[0].y) << 16);
        *(unsigned*)(AhiB + (srowB + (((unsigned)sc * 4u) ^ swsr))) = hv;
    }
    __syncthreads();

    #pragma unroll
    for (int kt = 0; kt < 16; ++kt) {
        const int cur = kt & 1;
        // B prefetch for kt+1 (L2 hit ~200-300 cyc; a full iteration to land)
        if (kt < 15)
            #pragma unroll
            for (int nf = 0; nf < 4; ++nf)
                bb[cur ^ 1][nf] = *(const bf16x8*)(Bw + nf * 16 * DD + (kt + 1) * 32);
        // A global prefetch, distance-3
        if (kt < 13)
            stg[(kt + 3) & 3] = *(const float2*)(aptr + (kt + 3) * 32);

        // A frags from swizzled LDS (slab kt = byte cols [kt*64, kt*64+64))
        const unsigned kb = (unsigned)kt * 64u;
        bf16x8 af0 = *(const bf16x8*)(AhiB + arow0 + ((kb + lq * 16u) ^ swlm));
        bf16x8 af1 = *(const bf16x8*)(AhiB + arow1 + ((kb + lq * 16u) ^ swlm));

        // 8 MFMA from the registers loaded last iteration
        #pragma unroll
        for (int nf = 0; nf < 4; ++nf) {
            acc[0][nf] = __builtin_amdgcn_mfma_f32_16x16x32_bf16(af0, bb[cur][nf], acc[0][nf], 0, 0, 0);
            acc[1][nf] = __builtin_amdgcn_mfma_f32_16x16x32_bf16(af1, bb[cur][nf], acc[1][nf], 0, 0, 0);
        }

        // write slab kt+1 (distinct LDS region -> no WAR with slab kt reads)
        if (kt < 15) {
            float2 x = stg[(kt + 1) & 3];
            unsigned hv = f2bf(x.x) | (f2bf(x.y) << 16);
            *(unsigned*)(AhiB + (srowB + (((unsigned)((kt + 1) * 64) + sc * 4u) ^ swsr))) = hv;
        }
        __syncthreads();
    }

    // ---- epilogue 1: tanh + dot v over this wave's n-slice (32 rows)
    const float* pb = p + (size_t)b * DD;
    float rowsum[2][4];
    #pragma unroll
    for (int mf = 0; mf < 2; ++mf)
        #pragma unroll
        for (int r = 0; r < 4; ++r) rowsum[mf][r] = 0.f;

    #pragma unroll
    for (int nf = 0; nf < 4; ++nf) {
        int n = wave * 64 + nf * 16 + lm;
        float pv = pb[n];
        float vv = va[n];
        #pragma unroll
        for (int mf = 0; mf < 2; ++mf)
            #pragma unroll
            for (int r = 0; r < 4; ++r)
                rowsum[mf][r] += fast_tanh(pv + acc[mf][nf][r]) * vv;
    }
    #pragma unroll
    for (int mf = 0; mf < 2; ++mf)
        #pragma unroll
        for (int r = 0; r < 4; ++r) {
            float s = rowsum[mf][r];
            s += __shfl_xor(s, 1);
            s += __shfl_xor(s, 2);
            s += __shfl_xor(s, 4);
            s += __shfl_xor(s, 8);
            rowsum[mf][r] = s;
        }
    if (lm == 0) {
        #pragma unroll
        for (int mf = 0; mf < 2; ++mf)
            #pragma unroll
            for (int r = 0; r < 4; ++r)
                sp[wave][mf * 16 + lq * 4 + r] = rowsum[mf][r];
    }
    __syncthreads();

    // ---- epilogue 2: scores for 32 rows, chunk-local softmax partials
    if (tid < 32) {
        float s = 0.f;
        #pragma unroll
        for (int w = 0; w < 8; ++w) s += sp[w][tid];
        score[m0 + tid] = s;
        float mx = s;
        #pragma unroll
        for (int off = 16; off > 0; off >>= 1) mx = fmaxf(mx, __shfl_xor(mx, off));
        float e = __expf(s - mx);
        float l = e;
        #pragma unroll
        for (int off = 16; off > 0; off >>= 1) l += __shfl_xor(l, off);
        elds[tid] = e;
        if (tid == 0) {
            ml[(size_t)blk * 2]     = mx;
            ml[(size_t)blk * 2 + 1] = l;
        }
    }
    __syncthreads();

    // ---- epilogue 3: ctx partial, exact fp32, enc re-read from L2/L3
    // (this block's own 64 KB tile, just streamed). Thread t owns d = t.
    {
        const float* erow = enc + m0 * DD + tid;
        float v = 0.f;
        #pragma unroll
        for (int s = 0; s < 32; ++s)
            v += elds[s] * erow[(size_t)s * DD];
        pctx[(size_t)blk * 512 + tid] = v;
    }
}

// ---------------------------------------------------------------------------
// Cross-chunk softmax combine: exact global M, L over 64 chunks; rescale
// pctx; write ctx and alignment. One block per batch.
__global__ void combine_k(const float* __restrict__ score, const float* __restrict__ ml,
                          const float* __restrict__ pctx, float* __restrict__ ctx,
                          float* __restrict__ align) {
    __shared__ float sc[64];
    __shared__ float MB, LB;
    const int b = blockIdx.x, tid = threadIdx.x;   // 256 threads
    if (tid < 64) sc[tid] = ml[(size_t)(b * 64 + tid) * 2];
    __syncthreads();
    if (tid == 0) {
        float M = sc[0];
        #pragma unroll
        for (int i = 1; i < 64; ++i) M = fmaxf(M, sc[i]);
        float L = 0.f;
        for (int i = 0; i < 64; ++i) {
            float w = __expf(sc[i] - M);
            L += w * ml[(size_t)(b * 64 + i) * 2 + 1];
            sc[i] = w;                  // only thread 0 touches sc here
        }
        MB = M;
        LB = L;
    }
    __syncthreads();
    const float M = MB, Linv = 1.0f / LB;
    float a0 = 0.f, a1 = 0.f;
    for (int i = 0; i < 64; ++i) {
        float w = sc[i];
        const float* pc = pctx + (size_t)(b * 64 + i) * 512;
        a0 += w * pc[tid];
        a1 += w * pc[tid + 256];
    }
    ctx[(size_t)b * DD + tid]       = a0 * Linv;
    ctx[(size_t)b * DD + tid + 256] = a1 * Linv;
    const float* sr = score + (size_t)b * SS;
    float* al = align + (size_t)b * SS;
    #pragma unroll
    for (int i = 0; i < 8; ++i) {
        int s = i * 256 + tid;
        al[s] = __expf(sr[s] - M) * Linv;
    }
}

// ---------------------------------------------------------------------------
extern "C" void kernel_launch(void* const* d_in, const int* in_sizes, int n_in,
                              void* d_out, int out_size, void* d_ws, size_t ws_size,
                              hipStream_t stream) {
    const float* dec = (const float*)d_in[0];  // [64,1,512]
    const float* enc = (const float*)d_in[1];  // [64,2048,512]
    const float* W   = (const float*)d_in[2];  // [1024,512]
    const float* bt  = (const float*)d_in[3];  // [512]
    const float* va  = (const float*)d_in[4];  // [512,1]

    float* out   = (float*)d_out;
    float* ctx   = out;                 // 32768 floats (output 0)
    float* align = out + BB * DD;       // 131072 floats (output 1)

    char*  ws    = (char*)d_ws;
    short* Bt    = (short*)ws;                    //  524288 B : bf16 W_enc^T [n][k]
    float* p     = (float*)(ws + 524288);         //  131072 B : dec @ W_dec + b_t
    float* score = (float*)(ws + 655360);         //  524288 B : raw scores
    float* ml    = (float*)(ws + 1179648);        //   32768 B : (max,sum) x 4096 chunks
    float* pctx  = (float*)(ws + 1212416);        // 8388608 B : partial contexts

    prep_w<<<64, 256, 0, stream>>>(W, Bt);
    prep_p<<<dim3(BB, 2), 256, 0, stream>>>(dec, W, bt, p);
    fused_k<<<BB * 64, 512, 0, stream>>>(enc, Bt, p, va, score, ml, pctx);
    combine_k<<<BB, 256, 0, stream>>>(score, ml, pctx, ctx, align);
}